// Round 3
// baseline (144.835 us; speedup 1.0000x reference)
//
#include <hip/hip_runtime.h>

typedef unsigned short u16;
typedef __attribute__((ext_vector_type(8))) short bf16x8;   // 8 bf16 (4 VGPRs)
typedef __attribute__((ext_vector_type(4))) float f32x4;

#define HEADS 12
#define HDIM  64
#define EMBED 768
#define TD    2304
#define SEQ   1024
#define MTOK  8192

// round-to-nearest-even f32 -> bf16
__device__ __forceinline__ u16 f2bf(float f) {
  union { float f; unsigned u; } x; x.f = f;
  unsigned r = x.u + 0x7fffu + ((x.u >> 16) & 1u);
  return (u16)(r >> 16);
}

__global__ void cast_kernel(const float* __restrict__ src, u16* __restrict__ dst, int n4) {
  int i = blockIdx.x * blockDim.x + threadIdx.x;
  int st = gridDim.x * blockDim.x;
  for (; i < n4; i += st) {
    float4 v = reinterpret_cast<const float4*>(src)[i];
    ushort4 o;
    o.x = f2bf(v.x); o.y = f2bf(v.y); o.z = f2bf(v.z); o.w = f2bf(v.w);
    reinterpret_cast<ushort4*>(dst)[i] = o;
  }
}

__device__ __forceinline__ void gload_lds16(const u16* g, u16* l) {
  __builtin_amdgcn_global_load_lds(
      (const __attribute__((address_space(1))) unsigned*)g,
      (__attribute__((address_space(3))) unsigned*)l, 16, 0, 0);
}

// C[M][N] = A[M][K] @ B[N][K]^T (+ bias[N]); A,B bf16; out bf16 or f32.
// 128x128 tile, BK=64, double-buffered LDS, 2-phase prefetch, XOR-swizzled
// tiles (stride 128B == 32-bank wrap without it). Swapped-operand MFMA so each
// lane holds 4 consecutive C columns -> vectorized epilogue.
template <bool OUT_BF16, bool HAS_BIAS>
__global__ __launch_bounds__(256) void gemm_bt(const u16* __restrict__ A,
                                               const u16* __restrict__ B,
                                               const float* __restrict__ bias,
                                               void* __restrict__ Cv, int K) {
  __shared__ u16 As[2][128 * 64];
  __shared__ u16 Bs[2][128 * 64];
  const int tid  = threadIdx.x;
  const int wave = tid >> 6, lane = tid & 63;
  const int wr = wave >> 1, wc = wave & 1;
  const int lr = lane & 15, g = lane >> 4;
  const int Ndim = gridDim.y * 128;

  const u16* Ag = A + (size_t)(blockIdx.x * 128) * K;
  const u16* Bg = B + (size_t)(blockIdx.y * 128) * K;

  // staging geometry: one gload_lds16 covers 8 rows x 8 chunks(16B).
  const int srow   = lane >> 3;                    // row within 8-row slot
  const int schunk = (lane & 7) ^ srow;            // pre-swizzled source chunk

  f32x4 acc[4][4];
#pragma unroll
  for (int m = 0; m < 4; ++m)
#pragma unroll
    for (int n = 0; n < 4; ++n) acc[m][n] = 0.f;

  auto stageAB = [&](int kt, int buf) {
#pragma unroll
    for (int c = 0; c < 4; ++c) {
      int slot = wave * 4 + c;                     // 0..15, 8 rows each
      int row  = slot * 8 + srow;
      gload_lds16(Ag + (size_t)row * K + kt + schunk * 8, &As[buf][slot * 512]);
      gload_lds16(Bg + (size_t)row * K + kt + schunk * 8, &Bs[buf][slot * 512]);
    }
  };

  const int NT = K >> 6;
  stageAB(0, 0);
  __syncthreads();
  int cur = 0;
  for (int t = 0; t < NT; ++t) {
    if (t + 1 < NT) stageAB((t + 1) << 6, cur ^ 1);

    bf16x8 af[4][2], bfr[4][2];
#pragma unroll
    for (int m = 0; m < 4; ++m)
#pragma unroll
      for (int kk = 0; kk < 2; ++kk) {
        int r = wr * 64 + m * 16 + lr;
        af[m][kk] = *reinterpret_cast<const bf16x8*>(
            &As[cur][r * 64 + (((kk * 4 + g) ^ (r & 7)) << 3)]);
      }
#pragma unroll
    for (int n = 0; n < 4; ++n)
#pragma unroll
      for (int kk = 0; kk < 2; ++kk) {
        int r = wc * 64 + n * 16 + lr;
        bfr[n][kk] = *reinterpret_cast<const bf16x8*>(
            &Bs[cur][r * 64 + (((kk * 4 + g) ^ (r & 7)) << 3)]);
      }
    // swapped operands: lane holds C[m0+lr][n0+4g+j]
#pragma unroll
    for (int m = 0; m < 4; ++m)
#pragma unroll
      for (int n = 0; n < 4; ++n) {
        acc[m][n] = __builtin_amdgcn_mfma_f32_16x16x32_bf16(bfr[n][0], af[m][0], acc[m][n], 0, 0, 0);
        acc[m][n] = __builtin_amdgcn_mfma_f32_16x16x32_bf16(bfr[n][1], af[m][1], acc[m][n], 0, 0, 0);
      }
    if (t + 1 < NT) __syncthreads();
    cur ^= 1;
  }

  const int row0 = blockIdx.x * 128 + wr * 64 + lr;
  const int col0 = blockIdx.y * 128 + wc * 64 + g * 4;
#pragma unroll
  for (int m = 0; m < 4; ++m)
#pragma unroll
    for (int n = 0; n < 4; ++n) {
      int row = row0 + m * 16;
      int col = col0 + n * 16;
      float4 bv = HAS_BIAS ? *reinterpret_cast<const float4*>(&bias[col])
                           : make_float4(0.f, 0.f, 0.f, 0.f);
      float v0 = acc[m][n][0] + bv.x, v1 = acc[m][n][1] + bv.y;
      float v2 = acc[m][n][2] + bv.z, v3 = acc[m][n][3] + bv.w;
      if (OUT_BF16) {
        ushort4 pw;
        pw.x = f2bf(v0); pw.y = f2bf(v1); pw.z = f2bf(v2); pw.w = f2bf(v3);
        *reinterpret_cast<ushort4*>(&((u16*)Cv)[(size_t)row * Ndim + col]) = pw;
      } else {
        *reinterpret_cast<float4*>(&((float*)Cv)[(size_t)row * Ndim + col]) =
            make_float4(v0, v1, v2, v3);
      }
    }
}

// Transpose V region of qkv into vt[bh][e][tok] (bf16).
__global__ __launch_bounds__(256) void vtrans_kernel(const u16* __restrict__ qkv,
                                                     u16* __restrict__ vt) {
  const int bh = blockIdx.x, kb = blockIdx.y;
  const int b = bh / HEADS, h = bh % HEADS;
  __shared__ u16 Ls[64 * 72];
  const int t = threadIdx.x;
  const int row = t >> 2, seg = t & 3;
  const u16* src = qkv + (size_t)(b * SEQ + kb * 64 + row) * TD + 2 * EMBED + h * HDIM + seg * 16;
  *reinterpret_cast<uint4*>(&Ls[row * 72 + seg * 16])     = *reinterpret_cast<const uint4*>(src);
  *reinterpret_cast<uint4*>(&Ls[row * 72 + seg * 16 + 8]) = *reinterpret_cast<const uint4*>(src + 8);
  __syncthreads();
  u16 tmp[16];
#pragma unroll
  for (int i = 0; i < 16; ++i) tmp[i] = Ls[(seg * 16 + i) * 72 + row];
  u16* dst = vt + (size_t)bh * (HDIM * SEQ) + (size_t)row * SEQ + kb * 64 + seg * 16;
  *reinterpret_cast<uint4*>(dst)     = *reinterpret_cast<const uint4*>(tmp);
  *reinterpret_cast<uint4*>(dst + 8) = *reinterpret_cast<const uint4*>(tmp + 8);
}

// Fused attention: block = (head-instance bh, 128-row Q tile), 4 waves.
// Double-buffered K/V with 2-phase prefetch; swapped QK^T; wave-private P.
__global__ __launch_bounds__(256) void attn_kernel(const u16* __restrict__ qkv,
                                                   const u16* __restrict__ vt,
                                                   u16* __restrict__ ctx) {
  const int bh = blockIdx.x;
  const int b = bh / HEADS, h = bh % HEADS;
  const int qt = blockIdx.y;
  const int tid = threadIdx.x, wave = tid >> 6, lane = tid & 63;
  const int lr = lane & 15, g = lane >> 4;

  __shared__ u16 Ks[2][64 * 64];  // [k-row][d], 16B chunks XOR-swizzled by row&7
  __shared__ u16 Vs[2][64 * 64];  // [e][k] (pre-transposed), same swizzle
  __shared__ u16 Ps[128 * 64];    // [m][k], 8B granules swizzled

  const size_t tok0 = (size_t)b * SEQ;
  const int q0 = qt * 128;
  const int mbase = wave * 32;

  bf16x8 qf[2][2];
#pragma unroll
  for (int mi = 0; mi < 2; ++mi)
#pragma unroll
    for (int dk = 0; dk < 2; ++dk)
      qf[mi][dk] = *reinterpret_cast<const bf16x8*>(
          qkv + (tok0 + q0 + mbase + mi * 16 + lr) * TD + h * HDIM + dk * 32 + g * 8);

  const int srow = lane >> 3;
  const int schunk = (lane & 7) ^ srow;
  const u16* vbase = vt + (size_t)bh * (HDIM * SEQ);

  auto stage = [&](int kb, int buf) {
#pragma unroll
    for (int c2 = 0; c2 < 2; ++c2) {
      int call = wave * 2 + c2;
      int row  = call * 8 + srow;
      gload_lds16(qkv + (tok0 + kb * 64 + row) * TD + EMBED + h * HDIM + schunk * 8,
                  &Ks[buf][call * 512]);
      gload_lds16(vbase + (size_t)row * SEQ + kb * 64 + schunk * 8,
                  &Vs[buf][call * 512]);
    }
  };

  f32x4 oacc[2][4];
#pragma unroll
  for (int mi = 0; mi < 2; ++mi)
#pragma unroll
    for (int e = 0; e < 4; ++e) oacc[mi][e] = 0.f;
  float psum[2] = {0.f, 0.f};

  stage(0, 0);
  __syncthreads();
  int cur = 0;
  for (int kb = 0; kb < 16; ++kb) {
    if (kb < 15) stage(kb + 1, cur ^ 1);

    // S^T = K @ Q^T
    bf16x8 ka[4][2];
#pragma unroll
    for (int n = 0; n < 4; ++n)
#pragma unroll
      for (int dk = 0; dk < 2; ++dk) {
        int r = n * 16 + lr;
        int c = dk * 4 + g;
        ka[n][dk] = *reinterpret_cast<const bf16x8*>(&Ks[cur][r * 64 + ((c ^ (r & 7)) << 3)]);
      }
#pragma unroll
    for (int mi = 0; mi < 2; ++mi) {
      int m = mbase + mi * 16 + lr;
      int pswz = (lr & 7) << 1;
#pragma unroll
      for (int n = 0; n < 4; ++n) {
        f32x4 s = 0.f;
        __builtin_amdgcn_s_setprio(1);
        s = __builtin_amdgcn_mfma_f32_16x16x32_bf16(ka[n][0], qf[mi][0], s, 0, 0, 0);
        s = __builtin_amdgcn_mfma_f32_16x16x32_bf16(ka[n][1], qf[mi][1], s, 0, 0, 0);
        __builtin_amdgcn_s_setprio(0);
        float e0 = __expf(s[0]), e1 = __expf(s[1]);
        float e2 = __expf(s[2]), e3 = __expf(s[3]);
        psum[mi] += (e0 + e1) + (e2 + e3);
        ushort4 pw;
        pw.x = f2bf(e0); pw.y = f2bf(e1); pw.z = f2bf(e2); pw.w = f2bf(e3);
        int gran = n * 4 + g;
        *reinterpret_cast<ushort4*>(&Ps[m * 64 + ((gran ^ pswz) << 2)]) = pw;
      }
    }

    // O += P @ V (P wave-private: no barrier between write and read)
    bf16x8 vb2[4][2];
#pragma unroll
    for (int e = 0; e < 4; ++e)
#pragma unroll
      for (int kk = 0; kk < 2; ++kk) {
        int r = e * 16 + lr;
        int c = kk * 4 + g;
        vb2[e][kk] = *reinterpret_cast<const bf16x8*>(&Vs[cur][r * 64 + ((c ^ (r & 7)) << 3)]);
      }
#pragma unroll
    for (int mi = 0; mi < 2; ++mi) {
      bf16x8 pa[2];
#pragma unroll
      for (int kk = 0; kk < 2; ++kk) {
        int r = mbase + mi * 16 + lr;
        int c = kk * 4 + g;
        pa[kk] = *reinterpret_cast<const bf16x8*>(&Ps[r * 64 + ((c ^ (r & 7)) << 3)]);
      }
      __builtin_amdgcn_s_setprio(1);
#pragma unroll
      for (int e = 0; e < 4; ++e) {
        oacc[mi][e] = __builtin_amdgcn_mfma_f32_16x16x32_bf16(pa[0], vb2[e][0], oacc[mi][e], 0, 0, 0);
        oacc[mi][e] = __builtin_amdgcn_mfma_f32_16x16x32_bf16(pa[1], vb2[e][1], oacc[mi][e], 0, 0, 0);
      }
      __builtin_amdgcn_s_setprio(0);
    }
    __syncthreads();
    cur ^= 1;
  }

  float scl[2][4];
#pragma unroll
  for (int mi = 0; mi < 2; ++mi) {
    float v = psum[mi];
    v += __shfl_xor(v, 16);
    v += __shfl_xor(v, 32);
    v = 0.125f / v;
#pragma unroll
    for (int j = 0; j < 4; ++j) scl[mi][j] = __shfl(v, 4 * g + j);
  }
#pragma unroll
  for (int mi = 0; mi < 2; ++mi)
#pragma unroll
    for (int e = 0; e < 4; ++e)
#pragma unroll
      for (int j = 0; j < 4; ++j) {
        float v = oacc[mi][e][j] * scl[mi][j];
        ctx[(tok0 + q0 + mbase + mi * 16 + 4 * g + j) * EMBED + h * HDIM + e * 16 + lr] = f2bf(v);
      }
}

extern "C" void kernel_launch(void* const* d_in, const int* in_sizes, int n_in,
                              void* d_out, int out_size, void* d_ws, size_t ws_size,
                              hipStream_t stream) {
  (void)in_sizes; (void)n_in; (void)out_size;
  const float* x     = (const float*)d_in[0];
  const float* Wqkv  = (const float*)d_in[1];
  const float* bqkv  = (const float*)d_in[2];
  const float* Wproj = (const float*)d_in[3];
  const float* bproj = (const float*)d_in[4];
  float* out = (float*)d_out;

  char* ws = (char*)d_ws;
  size_t off = 0;
  auto alloc = [&](size_t bytes) {
    char* p = ws + off;
    off += (bytes + 255) & ~(size_t)255;
    return p;
  };
  u16* xb     = (u16*)alloc((size_t)MTOK * EMBED * 2);
  u16* wqkvb  = (u16*)alloc((size_t)TD * EMBED * 2);
  u16* wprojb = (u16*)alloc((size_t)EMBED * EMBED * 2);
  u16* qkvb   = (u16*)alloc((size_t)MTOK * TD * 2);
  u16* ctxb   = (u16*)alloc((size_t)MTOK * EMBED * 2);
  if (off > ws_size) return;  // workspace too small: loud failure
  u16* vtb = xb;  // reuse: xb is dead after the QKV GEMM; vt is same size

  cast_kernel<<<dim3(1024), dim3(256), 0, stream>>>(x,     xb,     MTOK * EMBED / 4);
  cast_kernel<<<dim3(432),  dim3(256), 0, stream>>>(Wqkv,  wqkvb,  TD * EMBED / 4);
  cast_kernel<<<dim3(144),  dim3(256), 0, stream>>>(Wproj, wprojb, EMBED * EMBED / 4);

  // QKV projection: [8192,2304] = x @ Wqkv^T + b
  gemm_bt<true, true><<<dim3(64, 18), dim3(256), 0, stream>>>(xb, wqkvb, bqkv, qkvb, EMBED);
  // V transpose into vt[bh][e][tok] (aliases xb)
  vtrans_kernel<<<dim3(96, 16), dim3(256), 0, stream>>>(qkvb, vtb);
  // fused attention
  attn_kernel<<<dim3(96, 8), dim3(256), 0, stream>>>(qkvb, vtb, ctxb);
  // output projection: out = ctx @ Wproj^T + b (f32 out)
  gemm_bt<false, true><<<dim3(64, 6), dim3(256), 0, stream>>>(ctxb, wprojb, bproj, out, EMBED);
}

// Round 4
// 135.982 us; speedup vs baseline: 1.0651x; 1.0651x over previous
//
#include <hip/hip_runtime.h>

typedef unsigned short u16;
typedef __attribute__((ext_vector_type(8))) short bf16x8;   // 8 bf16 (4 VGPRs)
typedef __attribute__((ext_vector_type(4))) float f32x4;

#define HEADS 12
#define HDIM  64
#define EMBED 768
#define TD    2304
#define SEQ   1024
#define MTOK  8192

// round-to-nearest-even f32 -> bf16
__device__ __forceinline__ u16 f2bf(float f) {
  union { float f; unsigned u; } x; x.f = f;
  unsigned r = x.u + 0x7fffu + ((x.u >> 16) & 1u);
  return (u16)(r >> 16);
}

__global__ void cast_kernel(const float* __restrict__ src, u16* __restrict__ dst, int n4) {
  int i = blockIdx.x * blockDim.x + threadIdx.x;
  int st = gridDim.x * blockDim.x;
  for (; i < n4; i += st) {
    float4 v = reinterpret_cast<const float4*>(src)[i];
    ushort4 o;
    o.x = f2bf(v.x); o.y = f2bf(v.y); o.z = f2bf(v.z); o.w = f2bf(v.w);
    reinterpret_cast<ushort4*>(dst)[i] = o;
  }
}

__device__ __forceinline__ void gload_lds16(const u16* g, u16* l) {
  __builtin_amdgcn_global_load_lds(
      (const __attribute__((address_space(1))) unsigned*)g,
      (__attribute__((address_space(3))) unsigned*)l, 16, 0, 0);
}

__device__ __forceinline__ void memfence_bar() {
  asm volatile("" ::: "memory");
  __builtin_amdgcn_s_barrier();
  asm volatile("" ::: "memory");
}

// C[M][N] = A[M][K] @ B[N][K]^T (+ bias[N]); A,B bf16; out bf16 or f32.
// BM=256, BN=96, BK=64. 512 threads = 8 waves (4 row-groups x 2 col-groups),
// wave tile 64x48. 3-buffer LDS ring (132 KB), stage issued 3 K-tiles ahead,
// raw s_barrier + counted vmcnt (never 0 mid-loop). XOR-swizzled tiles.
template <bool OUT_BF16, bool HAS_BIAS>
__global__ __launch_bounds__(512, 2) void gemm_ring(const u16* __restrict__ A,
                                                    const u16* __restrict__ B,
                                                    const float* __restrict__ bias,
                                                    void* __restrict__ Cv,
                                                    int K, int NBN, int Ndim) {
  __shared__ u16 As[3][256 * 64];   // 3 x 32 KB
  __shared__ u16 Bs[3][96 * 64];    // 3 x 12 KB
  const int tid  = threadIdx.x;
  const int wave = tid >> 6, lane = tid & 63;
  const int wr = wave >> 1, wc = wave & 1;
  const int lr = lane & 15, g = lane >> 4;

  // XCD-aware swizzle (gridDim.x % 8 == 0), n-fastest tile decomposition.
  const int nwg = gridDim.x;
  const int swz = (blockIdx.x & 7) * (nwg >> 3) + (blockIdx.x >> 3);
  const int ny = swz % NBN, mx = swz / NBN;

  const u16* Ag = A + (size_t)(mx * 256) * K;
  const u16* Bg = B + (size_t)(ny * 96) * K;

  const int srow   = lane >> 3;             // row within 8-row slot
  const int schunk = (lane & 7) ^ srow;     // pre-swizzled source 16B-chunk

  f32x4 acc[4][3];
#pragma unroll
  for (int m = 0; m < 4; ++m)
#pragma unroll
    for (int n = 0; n < 3; ++n) acc[m][n] = 0.f;

  // per K-tile staging: A = 32 slots of 8 rows (4/wave), B = 12 slots
  // (1/wave + 1 extra for waves 0-3). gload_lds dest is wave-uniform.
  auto stageT = [&](int kt, int buf) {
    const int k0 = kt * 64;
#pragma unroll
    for (int c = 0; c < 4; ++c) {
      int slot = wave * 4 + c;
      int row  = slot * 8 + srow;
      gload_lds16(Ag + (size_t)row * K + k0 + schunk * 8, &As[buf][slot * 512]);
    }
    {
      int slot = wave;
      int row  = slot * 8 + srow;
      gload_lds16(Bg + (size_t)row * K + k0 + schunk * 8, &Bs[buf][slot * 512]);
    }
    if (wave < 4) {
      int slot = 8 + wave;
      int row  = slot * 8 + srow;
      gload_lds16(Bg + (size_t)row * K + k0 + schunk * 8, &Bs[buf][slot * 512]);
    }
  };

  const int NT = K >> 6;   // assumed >= 3
  stageT(0, 0);
  stageT(1, 1);
  stageT(2, 2);
  asm volatile("s_waitcnt vmcnt(10)" ::: "memory");  // kt0 complete (all waves)
  memfence_bar();

  int buf = 0;
  for (int t = 0; t < NT; ++t) {
    // frag reads from buf (compiler tracks deps for MFMA)
    bf16x8 af[4][2], bfr[3][2];
#pragma unroll
    for (int m = 0; m < 4; ++m)
#pragma unroll
      for (int kk = 0; kk < 2; ++kk) {
        int r = wr * 64 + m * 16 + lr;
        af[m][kk] = *reinterpret_cast<const bf16x8*>(
            &As[buf][r * 64 + (((kk * 4 + g) ^ (r & 7)) << 3)]);
      }
#pragma unroll
    for (int n = 0; n < 3; ++n)
#pragma unroll
      for (int kk = 0; kk < 2; ++kk) {
        int r = wc * 48 + n * 16 + lr;
        bfr[n][kk] = *reinterpret_cast<const bf16x8*>(
            &Bs[buf][r * 64 + (((kk * 4 + g) ^ (r & 7)) << 3)]);
      }
    // all reads of buf in regs before anyone overwrites it
    asm volatile("s_waitcnt lgkmcnt(0)" ::: "memory");
    memfence_bar();

    if (t + 3 < NT) stageT(t + 3, buf);

    __builtin_amdgcn_s_setprio(1);
#pragma unroll
    for (int m = 0; m < 4; ++m)
#pragma unroll
      for (int n = 0; n < 3; ++n) {
        acc[m][n] = __builtin_amdgcn_mfma_f32_16x16x32_bf16(bfr[n][0], af[m][0], acc[m][n], 0, 0, 0);
        acc[m][n] = __builtin_amdgcn_mfma_f32_16x16x32_bf16(bfr[n][1], af[m][1], acc[m][n], 0, 0, 0);
      }
    __builtin_amdgcn_s_setprio(0);

    // counted drain: guarantee kt(t+1) staged; keep later tiles in flight
    if (t + 4 <= NT)      { asm volatile("s_waitcnt vmcnt(10)" ::: "memory"); }
    else if (t + 3 == NT) { asm volatile("s_waitcnt vmcnt(5)"  ::: "memory"); }
    else if (t + 2 == NT) { asm volatile("s_waitcnt vmcnt(0)"  ::: "memory"); }
    if (t + 1 < NT) memfence_bar();

    buf = (buf == 2) ? 0 : buf + 1;
  }

  const int row0 = mx * 256 + wr * 64 + lr;
  const int col0 = ny * 96 + wc * 48 + g * 4;
#pragma unroll
  for (int m = 0; m < 4; ++m)
#pragma unroll
    for (int n = 0; n < 3; ++n) {
      int row = row0 + m * 16;
      int col = col0 + n * 16;
      float4 bv = HAS_BIAS ? *reinterpret_cast<const float4*>(&bias[col])
                           : make_float4(0.f, 0.f, 0.f, 0.f);
      float v0 = acc[m][n][0] + bv.x, v1 = acc[m][n][1] + bv.y;
      float v2 = acc[m][n][2] + bv.z, v3 = acc[m][n][3] + bv.w;
      if (OUT_BF16) {
        ushort4 pw;
        pw.x = f2bf(v0); pw.y = f2bf(v1); pw.z = f2bf(v2); pw.w = f2bf(v3);
        *reinterpret_cast<ushort4*>(&((u16*)Cv)[(size_t)row * Ndim + col]) = pw;
      } else {
        *reinterpret_cast<float4*>(&((float*)Cv)[(size_t)row * Ndim + col]) =
            make_float4(v0, v1, v2, v3);
      }
    }
}

// Transpose V region of qkv into vt[bh][e][tok] (bf16).
__global__ __launch_bounds__(256) void vtrans_kernel(const u16* __restrict__ qkv,
                                                     u16* __restrict__ vt) {
  const int bh = blockIdx.x, kb = blockIdx.y;
  const int b = bh / HEADS, h = bh % HEADS;
  __shared__ u16 Ls[64 * 72];
  const int t = threadIdx.x;
  const int row = t >> 2, seg = t & 3;
  const u16* src = qkv + (size_t)(b * SEQ + kb * 64 + row) * TD + 2 * EMBED + h * HDIM + seg * 16;
  *reinterpret_cast<uint4*>(&Ls[row * 72 + seg * 16])     = *reinterpret_cast<const uint4*>(src);
  *reinterpret_cast<uint4*>(&Ls[row * 72 + seg * 16 + 8]) = *reinterpret_cast<const uint4*>(src + 8);
  __syncthreads();
  u16 tmp[16];
#pragma unroll
  for (int i = 0; i < 16; ++i) tmp[i] = Ls[(seg * 16 + i) * 72 + row];
  u16* dst = vt + (size_t)bh * (HDIM * SEQ) + (size_t)row * SEQ + kb * 64 + seg * 16;
  *reinterpret_cast<uint4*>(dst)     = *reinterpret_cast<const uint4*>(tmp);
  *reinterpret_cast<uint4*>(dst + 8) = *reinterpret_cast<const uint4*>(tmp + 8);
}

// Fused attention (round-2 structure): block = (bh, 128-row Q tile), 4 waves.
__global__ __launch_bounds__(256) void attn_kernel(const u16* __restrict__ qkv,
                                                   const u16* __restrict__ vt,
                                                   u16* __restrict__ ctx) {
  const int bh = blockIdx.x;
  const int b = bh / HEADS, h = bh % HEADS;
  const int qt = blockIdx.y;
  const int tid = threadIdx.x, wave = tid >> 6, lane = tid & 63;
  const int lr = lane & 15, g = lane >> 4;

  __shared__ u16 Ks[64 * 64];   // [k-row][d], 16B chunks XOR-swizzled by row&7
  __shared__ u16 Vs[64 * 64];   // [e][k] (pre-transposed), same swizzle
  __shared__ u16 Ps[128 * 64];  // [m][k], 8B granules swizzled

  const size_t tok0 = (size_t)b * SEQ;
  const int q0 = qt * 128;
  const int mbase = wave * 32;

  bf16x8 qf[2][2];
#pragma unroll
  for (int mi = 0; mi < 2; ++mi)
#pragma unroll
    for (int dk = 0; dk < 2; ++dk)
      qf[mi][dk] = *reinterpret_cast<const bf16x8*>(
          qkv + (tok0 + q0 + mbase + mi * 16 + lr) * TD + h * HDIM + dk * 32 + g * 8);

  const int srow = lane >> 3;
  const int schunk = (lane & 7) ^ srow;

  f32x4 oacc[2][4];
#pragma unroll
  for (int mi = 0; mi < 2; ++mi)
#pragma unroll
    for (int e = 0; e < 4; ++e) oacc[mi][e] = 0.f;
  float psum[2] = {0.f, 0.f};

  for (int kb = 0; kb < 16; ++kb) {
#pragma unroll
    for (int c2 = 0; c2 < 2; ++c2) {
      int call = wave * 2 + c2;
      int row  = call * 8 + srow;
      gload_lds16(qkv + (tok0 + kb * 64 + row) * TD + EMBED + h * HDIM + schunk * 8,
                  &Ks[call * 512]);
      gload_lds16(vt + (size_t)bh * (HDIM * SEQ) + (size_t)row * SEQ + kb * 64 + schunk * 8,
                  &Vs[call * 512]);
    }
    __syncthreads();

    // S^T = K @ Q^T
    bf16x8 ka[4][2];
#pragma unroll
    for (int n = 0; n < 4; ++n)
#pragma unroll
      for (int dk = 0; dk < 2; ++dk) {
        int r = n * 16 + lr;
        int c = dk * 4 + g;
        ka[n][dk] = *reinterpret_cast<const bf16x8*>(&Ks[r * 64 + ((c ^ (r & 7)) << 3)]);
      }
#pragma unroll
    for (int mi = 0; mi < 2; ++mi) {
      int m = mbase + mi * 16 + lr;
      int pswz = (lr & 7) << 1;
#pragma unroll
      for (int n = 0; n < 4; ++n) {
        f32x4 s = 0.f;
        s = __builtin_amdgcn_mfma_f32_16x16x32_bf16(ka[n][0], qf[mi][0], s, 0, 0, 0);
        s = __builtin_amdgcn_mfma_f32_16x16x32_bf16(ka[n][1], qf[mi][1], s, 0, 0, 0);
        float e0 = __expf(s[0]), e1 = __expf(s[1]);
        float e2 = __expf(s[2]), e3 = __expf(s[3]);
        psum[mi] += (e0 + e1) + (e2 + e3);
        ushort4 pw;
        pw.x = f2bf(e0); pw.y = f2bf(e1); pw.z = f2bf(e2); pw.w = f2bf(e3);
        int gran = n * 4 + g;
        *reinterpret_cast<ushort4*>(&Ps[m * 64 + ((gran ^ pswz) << 2)]) = pw;
      }
    }

    // O += P @ V (P wave-private: no barrier between write and read)
    bf16x8 vb2[4][2];
#pragma unroll
    for (int e = 0; e < 4; ++e)
#pragma unroll
      for (int kk = 0; kk < 2; ++kk) {
        int r = e * 16 + lr;
        int c = kk * 4 + g;
        vb2[e][kk] = *reinterpret_cast<const bf16x8*>(&Vs[r * 64 + ((c ^ (r & 7)) << 3)]);
      }
#pragma unroll
    for (int mi = 0; mi < 2; ++mi) {
      bf16x8 pa[2];
#pragma unroll
      for (int kk = 0; kk < 2; ++kk) {
        int r = mbase + mi * 16 + lr;
        int c = kk * 4 + g;
        pa[kk] = *reinterpret_cast<const bf16x8*>(&Ps[r * 64 + ((c ^ (r & 7)) << 3)]);
      }
#pragma unroll
      for (int e = 0; e < 4; ++e) {
        oacc[mi][e] = __builtin_amdgcn_mfma_f32_16x16x32_bf16(pa[0], vb2[e][0], oacc[mi][e], 0, 0, 0);
        oacc[mi][e] = __builtin_amdgcn_mfma_f32_16x16x32_bf16(pa[1], vb2[e][1], oacc[mi][e], 0, 0, 0);
      }
    }
    __syncthreads();
  }

  float scl[2][4];
#pragma unroll
  for (int mi = 0; mi < 2; ++mi) {
    float v = psum[mi];
    v += __shfl_xor(v, 16);
    v += __shfl_xor(v, 32);
    v = 0.125f / v;
#pragma unroll
    for (int j = 0; j < 4; ++j) scl[mi][j] = __shfl(v, 4 * g + j);
  }
#pragma unroll
  for (int mi = 0; mi < 2; ++mi)
#pragma unroll
    for (int e = 0; e < 4; ++e)
#pragma unroll
      for (int j = 0; j < 4; ++j) {
        float v = oacc[mi][e][j] * scl[mi][j];
        ctx[(tok0 + q0 + mbase + mi * 16 + 4 * g + j) * EMBED + h * HDIM + e * 16 + lr] = f2bf(v);
      }
}

extern "C" void kernel_launch(void* const* d_in, const int* in_sizes, int n_in,
                              void* d_out, int out_size, void* d_ws, size_t ws_size,
                              hipStream_t stream) {
  (void)in_sizes; (void)n_in; (void)out_size;
  const float* x     = (const float*)d_in[0];
  const float* Wqkv  = (const float*)d_in[1];
  const float* bqkv  = (const float*)d_in[2];
  const float* Wproj = (const float*)d_in[3];
  const float* bproj = (const float*)d_in[4];
  float* out = (float*)d_out;

  char* ws = (char*)d_ws;
  size_t off = 0;
  auto alloc = [&](size_t bytes) {
    char* p = ws + off;
    off += (bytes + 255) & ~(size_t)255;
    return p;
  };
  u16* xb     = (u16*)alloc((size_t)MTOK * EMBED * 2);
  u16* wqkvb  = (u16*)alloc((size_t)TD * EMBED * 2);
  u16* wprojb = (u16*)alloc((size_t)EMBED * EMBED * 2);
  u16* qkvb   = (u16*)alloc((size_t)MTOK * TD * 2);
  u16* ctxb   = (u16*)alloc((size_t)MTOK * EMBED * 2);
  if (off > ws_size) return;  // workspace too small: loud failure
  u16* vtb = xb;  // reuse: xb is dead after the QKV GEMM; vt is same size

  cast_kernel<<<dim3(1024), dim3(256), 0, stream>>>(x,     xb,     MTOK * EMBED / 4);
  cast_kernel<<<dim3(432),  dim3(256), 0, stream>>>(Wqkv,  wqkvb,  TD * EMBED / 4);
  cast_kernel<<<dim3(144),  dim3(256), 0, stream>>>(Wproj, wprojb, EMBED * EMBED / 4);

  // QKV projection: [8192,2304] = x @ Wqkv^T + b   (grid 32x24 = 768 blocks)
  gemm_ring<true, true><<<dim3(768), dim3(512), 0, stream>>>(xb, wqkvb, bqkv, qkvb, EMBED, 24, TD);
  // V transpose into vt[bh][e][tok] (aliases xb)
  vtrans_kernel<<<dim3(96, 16), dim3(256), 0, stream>>>(qkvb, vtb);
  // fused attention
  attn_kernel<<<dim3(96, 8), dim3(256), 0, stream>>>(qkvb, vtb, ctxb);
  // output projection: out = ctx @ Wproj^T + b (f32 out)  (grid 32x8 = 256 blocks)
  gemm_ring<false, true><<<dim3(256), dim3(512), 0, stream>>>(ctxb, wprojb, bproj, out, EMBED, 8, EMBED);
}

// Round 6
// 125.092 us; speedup vs baseline: 1.1578x; 1.0871x over previous
//
#include <hip/hip_runtime.h>

typedef unsigned short u16;
typedef __attribute__((ext_vector_type(8))) short bf16x8;   // 8 bf16 (4 VGPRs)
typedef __attribute__((ext_vector_type(4))) float f32x4;

#define HEADS 12
#define HDIM  64
#define EMBED 768
#define TD    2304
#define SEQ   1024
#define MTOK  8192
#define GK    768
#define GNT   12   // GK / 64

// round-to-nearest-even f32 -> bf16
__device__ __forceinline__ u16 f2bf(float f) {
  union { float f; unsigned u; } x; x.f = f;
  unsigned r = x.u + 0x7fffu + ((x.u >> 16) & 1u);
  return (u16)(r >> 16);
}

// all three f32->bf16 casts in one launch
__global__ void cast3_kernel(const float* __restrict__ x, const float* __restrict__ wq,
                             const float* __restrict__ wp, u16* __restrict__ xb,
                             u16* __restrict__ wqb, u16* __restrict__ wpb) {
  const int N1 = MTOK * EMBED / 4, N2 = TD * EMBED / 4, N3 = EMBED * EMBED / 4;
  int i = blockIdx.x * blockDim.x + threadIdx.x;
  int st = gridDim.x * blockDim.x;
  for (; i < N1 + N2 + N3; i += st) {
    const float* s; u16* d; int j;
    if (i < N1)           { s = x;  d = xb;  j = i; }
    else if (i < N1 + N2) { s = wq; d = wqb; j = i - N1; }
    else                  { s = wp; d = wpb; j = i - N1 - N2; }
    float4 v = reinterpret_cast<const float4*>(s)[j];
    ushort4 o;
    o.x = f2bf(v.x); o.y = f2bf(v.y); o.z = f2bf(v.z); o.w = f2bf(v.w);
    reinterpret_cast<ushort4*>(d)[j] = o;
  }
}

__device__ __forceinline__ void gload_lds16(const u16* g, u16* l) {
  __builtin_amdgcn_global_load_lds(
      (const __attribute__((address_space(1))) unsigned*)g,
      (__attribute__((address_space(3))) unsigned*)l, 16, 0, 0);
}

__device__ __forceinline__ void memfence_bar() {
  asm volatile("" ::: "memory");
  __builtin_amdgcn_s_barrier();
  asm volatile("" ::: "memory");
}

// C[M][N] = A[M][K=768] @ B[N][768]^T + bias; out bf16 or f32.
// BM=128, BN=96, BK=64; 256 thr = 4 waves (2x2), wave tile 64x48.
// A ring-3 + B dbuf (72 KB -> 2 blocks/CU). Two fine phases per K-tile,
// counted vmcnt(4) once per tile, raw barriers, XOR-swizzled tiles.
template <bool OUT_BF16>
__global__ __launch_bounds__(256, 2) void gemm_phase(const u16* __restrict__ A,
                                                     const u16* __restrict__ B,
                                                     const float* __restrict__ bias,
                                                     void* __restrict__ Cv,
                                                     int NBN, int Ndim) {
  __shared__ u16 As[3][128 * 64];   // 3 x 16 KB
  __shared__ u16 Bs[2][96 * 64];    // 2 x 12 KB
  const int tid  = threadIdx.x;
  const int wave = tid >> 6, lane = tid & 63;
  const int wr = wave >> 1, wc = wave & 1;
  const int lr = lane & 15, g = lane >> 4;

  const int nwg = gridDim.x;
  const int swz = (blockIdx.x & 7) * (nwg >> 3) + (blockIdx.x >> 3);
  const int ny = swz % NBN, mx = swz / NBN;

  const u16* Ag = A + (size_t)(mx * 128) * GK;
  const u16* Bg = B + (size_t)(ny * 96) * GK;

  const int srow   = lane >> 3;             // row within 8-row slot
  const int schunk = (lane & 7) ^ srow;     // pre-swizzled source 16B-chunk

  auto stageA = [&](int kt, int buf) {      // 4 gloads/thread
#pragma unroll
    for (int c = 0; c < 4; ++c) {
      int slot = wave * 4 + c;              // 0..15
      int row  = slot * 8 + srow;
      gload_lds16(Ag + (size_t)row * GK + kt * 64 + schunk * 8, &As[buf][slot * 512]);
    }
  };
  auto stageB = [&](int kt, int buf) {      // 3 gloads/thread
#pragma unroll
    for (int c = 0; c < 3; ++c) {
      int slot = wave * 3 + c;              // 0..11
      int row  = slot * 8 + srow;
      gload_lds16(Bg + (size_t)row * GK + kt * 64 + schunk * 8, &Bs[buf][slot * 512]);
    }
  };

  f32x4 acc[4][3];
#pragma unroll
  for (int m = 0; m < 4; ++m)
#pragma unroll
    for (int n = 0; n < 3; ++n) acc[m][n] = 0.f;

  // prologue: A(0),B(0),A(1) issued; wait A(0)+B(0) (leave A(1) in flight)
  stageA(0, 0);
  stageB(0, 0);
  stageA(1, 1);
  asm volatile("s_waitcnt vmcnt(4)" ::: "memory");
  memfence_bar();

  int ra = 0, rb = 0;
  for (int t = 0; t < GNT; ++t) {
    // ---- phase A: reads (af all + bf ks0), stage-issue, bar, MFMA ks0 ----
    bf16x8 af[4][2], bf0[3], bf1[3];
#pragma unroll
    for (int m = 0; m < 4; ++m)
#pragma unroll
      for (int kk = 0; kk < 2; ++kk) {
        int r = wr * 64 + m * 16 + lr;
        af[m][kk] = *reinterpret_cast<const bf16x8*>(
            &As[ra][r * 64 + (((kk * 4 + g) ^ (r & 7)) << 3)]);
      }
#pragma unroll
    for (int n = 0; n < 3; ++n) {
      int r = wc * 48 + n * 16 + lr;
      bf0[n] = *reinterpret_cast<const bf16x8*>(&Bs[rb][r * 64 + ((g ^ (r & 7)) << 3)]);
    }
    if (t + 1 < GNT) stageB(t + 1, rb ^ 1);
    if (t + 2 < GNT) stageA(t + 2, ra >= 1 ? ra - 1 : 2);
    memfence_bar();
    asm volatile("s_waitcnt lgkmcnt(0)" ::: "memory");
    __builtin_amdgcn_sched_barrier(0);
    __builtin_amdgcn_s_setprio(1);
#pragma unroll
    for (int m = 0; m < 4; ++m)
#pragma unroll
      for (int n = 0; n < 3; ++n)
        acc[m][n] = __builtin_amdgcn_mfma_f32_16x16x32_bf16(bf0[n], af[m][0], acc[m][n], 0, 0, 0);
    __builtin_amdgcn_s_setprio(0);

    // ---- phase B: reads (bf ks1), bar, MFMA ks1, counted vmcnt, bar ----
#pragma unroll
    for (int n = 0; n < 3; ++n) {
      int r = wc * 48 + n * 16 + lr;
      bf1[n] = *reinterpret_cast<const bf16x8*>(&Bs[rb][r * 64 + (((4 + g) ^ (r & 7)) << 3)]);
    }
    memfence_bar();
    asm volatile("s_waitcnt lgkmcnt(0)" ::: "memory");
    __builtin_amdgcn_sched_barrier(0);
    __builtin_amdgcn_s_setprio(1);
#pragma unroll
    for (int m = 0; m < 4; ++m)
#pragma unroll
      for (int n = 0; n < 3; ++n)
        acc[m][n] = __builtin_amdgcn_mfma_f32_16x16x32_bf16(bf1[n], af[m][1], acc[m][n], 0, 0, 0);
    __builtin_amdgcn_s_setprio(0);

    if (t < GNT - 2) {
      asm volatile("s_waitcnt vmcnt(4)" ::: "memory");  // next tile staged; A(t+2) in flight
      memfence_bar();
    } else if (t == GNT - 2) {
      asm volatile("s_waitcnt vmcnt(0)" ::: "memory");  // last B-tile drain
      memfence_bar();
    }
    ra = (ra == 2) ? 0 : ra + 1;
    rb ^= 1;
  }

  const int row0 = mx * 128 + wr * 64 + lr;
  const int col0 = ny * 96 + wc * 48 + g * 4;
#pragma unroll
  for (int m = 0; m < 4; ++m)
#pragma unroll
    for (int n = 0; n < 3; ++n) {
      int row = row0 + m * 16;
      int col = col0 + n * 16;
      float4 bv = *reinterpret_cast<const float4*>(&bias[col]);
      float v0 = acc[m][n][0] + bv.x, v1 = acc[m][n][1] + bv.y;
      float v2 = acc[m][n][2] + bv.z, v3 = acc[m][n][3] + bv.w;
      if (OUT_BF16) {
        ushort4 pw;
        pw.x = f2bf(v0); pw.y = f2bf(v1); pw.z = f2bf(v2); pw.w = f2bf(v3);
        *reinterpret_cast<ushort4*>(&((u16*)Cv)[(size_t)row * Ndim + col]) = pw;
      } else {
        *reinterpret_cast<float4*>(&((float*)Cv)[(size_t)row * Ndim + col]) =
            make_float4(v0, v1, v2, v3);
      }
    }
}

// Transpose V region of qkv into vt[bh][e][tok] (bf16).
__global__ __launch_bounds__(256) void vtrans_kernel(const u16* __restrict__ qkv,
                                                     u16* __restrict__ vt) {
  const int bh = blockIdx.x, kb = blockIdx.y;
  const int b = bh / HEADS, h = bh % HEADS;
  __shared__ u16 Ls[64 * 72];
  const int t = threadIdx.x;
  const int row = t >> 2, seg = t & 3;
  const u16* src = qkv + (size_t)(b * SEQ + kb * 64 + row) * TD + 2 * EMBED + h * HDIM + seg * 16;
  *reinterpret_cast<uint4*>(&Ls[row * 72 + seg * 16])     = *reinterpret_cast<const uint4*>(src);
  *reinterpret_cast<uint4*>(&Ls[row * 72 + seg * 16 + 8]) = *reinterpret_cast<const uint4*>(src + 8);
  __syncthreads();
  u16 tmp[16];
#pragma unroll
  for (int i = 0; i < 16; ++i) tmp[i] = Ls[(seg * 16 + i) * 72 + row];
  u16* dst = vt + (size_t)bh * (HDIM * SEQ) + (size_t)row * SEQ + kb * 64 + seg * 16;
  *reinterpret_cast<uint4*>(dst)     = *reinterpret_cast<const uint4*>(tmp);
  *reinterpret_cast<uint4*>(dst + 8) = *reinterpret_cast<const uint4*>(tmp + 8);
}

// Fused attention: block = (bh, 128-row Q tile), 4 waves. K/V double-buffered,
// raw barriers + end-of-tile vmcnt(0) (stage issued at tile start, latency
// covered by 32 MFMA + exp). Swapped QK^T; wave-private P.
__global__ __launch_bounds__(256, 3) void attn_kernel(const u16* __restrict__ qkv,
                                                      const u16* __restrict__ vt,
                                                      u16* __restrict__ ctx) {
  const int bh = blockIdx.x;
  const int b = bh / HEADS, h = bh % HEADS;
  const int qt = blockIdx.y;
  const int tid = threadIdx.x, wave = tid >> 6, lane = tid & 63;
  const int lr = lane & 15, g = lane >> 4;

  __shared__ u16 Ks[2][64 * 64];  // [k-row][d], swizzled chunks
  __shared__ u16 Vs[2][64 * 64];  // [e][k] (pre-transposed), same swizzle
  __shared__ u16 Ps[128 * 64];    // [m][k], 8B granules swizzled

  const size_t tok0 = (size_t)b * SEQ;
  const int q0 = qt * 128;
  const int mbase = wave * 32;

  bf16x8 qf[2][2];
#pragma unroll
  for (int mi = 0; mi < 2; ++mi)
#pragma unroll
    for (int dk = 0; dk < 2; ++dk)
      qf[mi][dk] = *reinterpret_cast<const bf16x8*>(
          qkv + (tok0 + q0 + mbase + mi * 16 + lr) * TD + h * HDIM + dk * 32 + g * 8);

  const int srow = lane >> 3;
  const int schunk = (lane & 7) ^ srow;
  const u16* vbase = vt + (size_t)bh * (HDIM * SEQ);

  auto stage = [&](int kb, int buf) {       // 4 gloads/thread
#pragma unroll
    for (int c2 = 0; c2 < 2; ++c2) {
      int call = wave * 2 + c2;
      int row  = call * 8 + srow;
      gload_lds16(qkv + (tok0 + kb * 64 + row) * TD + EMBED + h * HDIM + schunk * 8,
                  &Ks[buf][call * 512]);
      gload_lds16(vbase + (size_t)row * SEQ + kb * 64 + schunk * 8,
                  &Vs[buf][call * 512]);
    }
  };

  f32x4 oacc[2][4];
#pragma unroll
  for (int mi = 0; mi < 2; ++mi)
#pragma unroll
    for (int e = 0; e < 4; ++e) oacc[mi][e] = 0.f;
  float psum[2] = {0.f, 0.f};

  stage(0, 0);
  asm volatile("s_waitcnt vmcnt(0)" ::: "memory");
  memfence_bar();

  int cur = 0;
  for (int kb = 0; kb < 16; ++kb) {
    if (kb < 15) stage(kb + 1, cur ^ 1);

    // S^T = K @ Q^T
    bf16x8 ka[4][2];
#pragma unroll
    for (int n = 0; n < 4; ++n)
#pragma unroll
      for (int dk = 0; dk < 2; ++dk) {
        int r = n * 16 + lr;
        int c = dk * 4 + g;
        ka[n][dk] = *reinterpret_cast<const bf16x8*>(&Ks[cur][r * 64 + ((c ^ (r & 7)) << 3)]);
      }
#pragma unroll
    for (int mi = 0; mi < 2; ++mi) {
      int m = mbase + mi * 16 + lr;
      int pswz = (lr & 7) << 1;
#pragma unroll
      for (int n = 0; n < 4; ++n) {
        f32x4 s = 0.f;
        __builtin_amdgcn_s_setprio(1);
        s = __builtin_amdgcn_mfma_f32_16x16x32_bf16(ka[n][0], qf[mi][0], s, 0, 0, 0);
        s = __builtin_amdgcn_mfma_f32_16x16x32_bf16(ka[n][1], qf[mi][1], s, 0, 0, 0);
        __builtin_amdgcn_s_setprio(0);
        float e0 = __expf(s[0]), e1 = __expf(s[1]);
        float e2 = __expf(s[2]), e3 = __expf(s[3]);
        psum[mi] += (e0 + e1) + (e2 + e3);
        ushort4 pw;
        pw.x = f2bf(e0); pw.y = f2bf(e1); pw.z = f2bf(e2); pw.w = f2bf(e3);
        int gran = n * 4 + g;
        *reinterpret_cast<ushort4*>(&Ps[m * 64 + ((gran ^ pswz) << 2)]) = pw;
      }
    }

    // O += P @ V (P wave-private)
    bf16x8 vb2[4][2];
#pragma unroll
    for (int e = 0; e < 4; ++e)
#pragma unroll
      for (int kk = 0; kk < 2; ++kk) {
        int r = e * 16 + lr;
        int c = kk * 4 + g;
        vb2[e][kk] = *reinterpret_cast<const bf16x8*>(&Vs[cur][r * 64 + ((c ^ (r & 7)) << 3)]);
      }
#pragma unroll
    for (int mi = 0; mi < 2; ++mi) {
      bf16x8 pa[2];
#pragma unroll
      for (int kk = 0; kk < 2; ++kk) {
        int r = mbase + mi * 16 + lr;
        int c = kk * 4 + g;
        pa[kk] = *reinterpret_cast<const bf16x8*>(&Ps[r * 64 + ((c ^ (r & 7)) << 3)]);
      }
      __builtin_amdgcn_s_setprio(1);
#pragma unroll
      for (int e = 0; e < 4; ++e) {
        oacc[mi][e] = __builtin_amdgcn_mfma_f32_16x16x32_bf16(pa[0], vb2[e][0], oacc[mi][e], 0, 0, 0);
        oacc[mi][e] = __builtin_amdgcn_mfma_f32_16x16x32_bf16(pa[1], vb2[e][1], oacc[mi][e], 0, 0, 0);
      }
      __builtin_amdgcn_s_setprio(0);
    }

    if (kb < 15) {
      asm volatile("s_waitcnt vmcnt(0)" ::: "memory");  // next K/V staged
      memfence_bar();
    }
    cur ^= 1;
  }

  float scl[2][4];
#pragma unroll
  for (int mi = 0; mi < 2; ++mi) {
    float v = psum[mi];
    v += __shfl_xor(v, 16);
    v += __shfl_xor(v, 32);
    v = 0.125f / v;
#pragma unroll
    for (int j = 0; j < 4; ++j) scl[mi][j] = __shfl(v, 4 * g + j);
  }
#pragma unroll
  for (int mi = 0; mi < 2; ++mi)
#pragma unroll
    for (int e = 0; e < 4; ++e)
#pragma unroll
      for (int j = 0; j < 4; ++j) {
        float v = oacc[mi][e][j] * scl[mi][j];
        ctx[(tok0 + q0 + mbase + mi * 16 + 4 * g + j) * EMBED + h * HDIM + e * 16 + lr] = f2bf(v);
      }
}

extern "C" void kernel_launch(void* const* d_in, const int* in_sizes, int n_in,
                              void* d_out, int out_size, void* d_ws, size_t ws_size,
                              hipStream_t stream) {
  (void)in_sizes; (void)n_in; (void)out_size;
  const float* x     = (const float*)d_in[0];
  const float* Wqkv  = (const float*)d_in[1];
  const float* bqkv  = (const float*)d_in[2];
  const float* Wproj = (const float*)d_in[3];
  const float* bproj = (const float*)d_in[4];
  float* out = (float*)d_out;

  char* ws = (char*)d_ws;
  size_t off = 0;
  auto alloc = [&](size_t bytes) {
    char* p = ws + off;
    off += (bytes + 255) & ~(size_t)255;
    return p;
  };
  u16* xb     = (u16*)alloc((size_t)MTOK * EMBED * 2);
  u16* wqkvb  = (u16*)alloc((size_t)TD * EMBED * 2);
  u16* wprojb = (u16*)alloc((size_t)EMBED * EMBED * 2);
  u16* qkvb   = (u16*)alloc((size_t)MTOK * TD * 2);
  u16* ctxb   = (u16*)alloc((size_t)MTOK * EMBED * 2);
  if (off > ws_size) return;  // workspace too small: loud failure
  u16* vtb = xb;  // reuse: xb is dead after the QKV GEMM; vt is same size

  cast3_kernel<<<dim3(2048), dim3(256), 0, stream>>>(x, Wqkv, Wproj, xb, wqkvb, wprojb);

  // QKV projection: grid 64x24 = 1536 blocks = 3.0 rounds @ 2 blocks/CU
  gemm_phase<true><<<dim3(1536), dim3(256), 0, stream>>>(xb, wqkvb, bqkv, qkvb, 24, TD);
  // V transpose into vt[bh][e][tok] (aliases xb)
  vtrans_kernel<<<dim3(96, 16), dim3(256), 0, stream>>>(qkvb, vtb);
  // fused attention
  attn_kernel<<<dim3(96, 8), dim3(256), 0, stream>>>(qkvb, vtb, ctxb);
  // output projection: grid 64x8 = 512 blocks = 1.0 round @ 2 blocks/CU
  gemm_phase<false><<<dim3(512), dim3(256), 0, stream>>>(ctxb, wprojb, bproj, out, 8, EMBED);
}